// Round 5
// baseline (418.962 us; speedup 1.0000x reference)
//
#include <hip/hip_runtime.h>

// 3-layer GCN + mean pool. bf16 storage / MFMA / fp32 accumulate.
// R5: fully fused per-layer kernel — aggregation accumulates the MFMA
// A-fragment directly in registers (4 lanes per node, 16B chunks matching
// the 16x16x32 A layout), B-fragments stream from global (L1/L2-resident
// 32KB transposed W). No LDS, no __syncthreads, no intermediate agg buffer.

#define DIN 30
#define HD  128

typedef __attribute__((ext_vector_type(8))) short v8s;
typedef __attribute__((ext_vector_type(4))) float v4f;

static __device__ __forceinline__ unsigned short f2bf(float f) {
  unsigned int u = __float_as_uint(f);
  u += 0x7fffu + ((u >> 16) & 1u);   // RNE
  return (unsigned short)(u >> 16);
}
static __device__ __forceinline__ float bf2f(unsigned short s) {
  return __uint_as_float(((unsigned int)s) << 16);
}
static __device__ __forceinline__ float bflo(unsigned int u) {
  return __uint_as_float(u << 16);
}
static __device__ __forceinline__ float bfhi(unsigned int u) {
  return __uint_as_float(u & 0xffff0000u);
}

// ---------------- preprocessing ----------------
__global__ void k_zero_i32(int* __restrict__ p, int n) {
  int i = blockIdx.x * blockDim.x + threadIdx.x;
  if (i < n) p[i] = 0;
}

__global__ void k_degree(const int* __restrict__ dst, int* __restrict__ deg, int E) {
  int e = blockIdx.x * blockDim.x + threadIdx.x;
  if (e < E) atomicAdd(&deg[dst[e]], 1);
}

__global__ void k_dinv(const int* __restrict__ deg, float* __restrict__ dinv, int N) {
  int i = blockIdx.x * blockDim.x + threadIdx.x;
  if (i < N) dinv[i] = rsqrtf((float)(1 + deg[i]));
}

__global__ void k_scan1(const int* __restrict__ deg, int* __restrict__ bsum, int N) {
  __shared__ int s[256];
  int tid = threadIdx.x;
  int base = blockIdx.x * 1024 + tid * 4;
  int t = 0;
#pragma unroll
  for (int j = 0; j < 4; ++j) { int idx = base + j; if (idx < N) t += deg[idx]; }
  s[tid] = t; __syncthreads();
  for (int d = 128; d > 0; d >>= 1) { if (tid < d) s[tid] += s[tid + d]; __syncthreads(); }
  if (tid == 0) bsum[blockIdx.x] = s[0];
}

__global__ void k_scan2(const int* __restrict__ bsum, int* __restrict__ boff, int nb) {
  __shared__ int s[256];
  int tid = threadIdx.x;
  int v = (tid < nb) ? bsum[tid] : 0;
  s[tid] = v; __syncthreads();
  for (int d = 1; d < 256; d <<= 1) {
    int t = (tid >= d) ? s[tid - d] : 0;
    __syncthreads();
    s[tid] += t;
    __syncthreads();
  }
  boff[tid] = s[tid] - v;
}

__global__ void k_scan3(const int* __restrict__ deg, const int* __restrict__ boff,
                        int* __restrict__ rowptr, int* __restrict__ cursor, int N) {
  __shared__ int s[256];
  int tid = threadIdx.x;
  int base = blockIdx.x * 1024 + tid * 4;
  int v[4]; int t = 0;
#pragma unroll
  for (int j = 0; j < 4; ++j) { int idx = base + j; v[j] = (idx < N) ? deg[idx] : 0; t += v[j]; }
  s[tid] = t; __syncthreads();
  for (int d = 1; d < 256; d <<= 1) {
    int u = (tid >= d) ? s[tid - d] : 0;
    __syncthreads();
    s[tid] += u;
    __syncthreads();
  }
  int run = boff[blockIdx.x] + s[tid] - t;
#pragma unroll
  for (int j = 0; j < 4; ++j) {
    int idx = base + j;
    if (idx < N) { rowptr[idx] = run; cursor[idx] = run; }
    run += v[j];
    if (idx == N - 1) rowptr[N] = run;
  }
}

// CSR scatter with fused per-edge weight: ecw[pos] = (src, dinv[src]*dinv[dst])
__global__ void k_scatter(const int* __restrict__ src, const int* __restrict__ dst,
                          const float* __restrict__ dinv,
                          int* __restrict__ cursor, uint2* __restrict__ ecw, int E) {
  int e = blockIdx.x * blockDim.x + threadIdx.x;
  if (e < E) {
    int s = src[e], d = dst[e];
    int pos = atomicAdd(&cursor[d], 1);
    float w = dinv[s] * dinv[d];
    ecw[pos] = make_uint2((unsigned int)s, __float_as_uint(w));
  }
}

// W [K][128] fp32 -> WT [128][Kstore] bf16 (zero-pad k >= Kreal)
__global__ void k_wt(const float* __restrict__ W, unsigned short* __restrict__ WT,
                     int Kreal, int Kstore) {
  int n = blockIdx.x;
  for (int k = threadIdx.x; k < Kstore; k += blockDim.x)
    WT[n * Kstore + k] = (k < Kreal) ? f2bf(W[k * 128 + n]) : (unsigned short)0;
}

// x [N][30] fp32 -> xb [N][32] bf16 (features 30,31 zero)
__global__ void k_xcast(const float* __restrict__ x, unsigned short* __restrict__ xb, int N) {
  int idx = blockIdx.x * blockDim.x + threadIdx.x;
  if (idx >= N * 32) return;
  int n = idx >> 5, f = idx & 31;
  float v = (f < DIN) ? x[(size_t)n * DIN + f] : 0.f;
  xb[idx] = f2bf(v);
}

// ---------------- fused aggregate + MFMA GEMM ----------------
// h [N][K] bf16, WT [128][K] bf16, C = relu((S h) WT^T + b) [N][128] bf16.
// One wave = 16 nodes. Lane (quad,l15): aggregates features kk*32+quad*8..+7
// of node (base+l15) into fp32 regs == its MFMA A-fragment. D layout:
// row = quad*4+i, col = l15 (verified m89).
template <int K>
__global__ __launch_bounds__(256) void k_fused(const unsigned short* __restrict__ h,
                                               const unsigned short* __restrict__ WT,
                                               const float* __restrict__ b,
                                               const int* __restrict__ rowptr,
                                               const uint2* __restrict__ ecw,
                                               const float* __restrict__ dinv,
                                               unsigned short* __restrict__ C, int N) {
  constexpr int CH = K / 32;   // A-fragments per lane
  constexpr int RC = K / 8;    // uint4 chunks per feature row
  int tid = threadIdx.x;
  int wave = blockIdx.x * 4 + (tid >> 6);
  int lane = tid & 63;
  int l15 = lane & 15, quad = lane >> 4;
  int nodeBase = wave * 16;
  int node = nodeBase + l15;
  bool vn = node < N;

  const uint4* hp = (const uint4*)h;
  float acc[CH][8];
  float di = vn ? dinv[node] : 0.f;
  float ws = di * di;
#pragma unroll
  for (int kk = 0; kk < CH; ++kk) {
    uint4 u = make_uint4(0u, 0u, 0u, 0u);
    if (vn) u = hp[(size_t)node * RC + kk * 4 + quad];
    acc[kk][0] = bflo(u.x) * ws; acc[kk][1] = bfhi(u.x) * ws;
    acc[kk][2] = bflo(u.y) * ws; acc[kk][3] = bfhi(u.y) * ws;
    acc[kk][4] = bflo(u.z) * ws; acc[kk][5] = bfhi(u.z) * ws;
    acc[kk][6] = bflo(u.w) * ws; acc[kk][7] = bfhi(u.w) * ws;
  }
  int e0 = vn ? rowptr[node] : 0;
  int e1 = vn ? rowptr[node + 1] : 0;
  int e = e0;
  for (; e + 2 <= e1; e += 2) {
    uint2 p0 = ecw[e], p1 = ecw[e + 1];
    float w0 = __uint_as_float(p0.y), w1 = __uint_as_float(p1.y);
    uint4 v0[CH], v1[CH];
#pragma unroll
    for (int kk = 0; kk < CH; ++kk) {
      v0[kk] = hp[(size_t)p0.x * RC + kk * 4 + quad];
      v1[kk] = hp[(size_t)p1.x * RC + kk * 4 + quad];
    }
#pragma unroll
    for (int kk = 0; kk < CH; ++kk) {
      acc[kk][0] = fmaf(bflo(v0[kk].x), w0, acc[kk][0]);
      acc[kk][1] = fmaf(bfhi(v0[kk].x), w0, acc[kk][1]);
      acc[kk][2] = fmaf(bflo(v0[kk].y), w0, acc[kk][2]);
      acc[kk][3] = fmaf(bfhi(v0[kk].y), w0, acc[kk][3]);
      acc[kk][4] = fmaf(bflo(v0[kk].z), w0, acc[kk][4]);
      acc[kk][5] = fmaf(bfhi(v0[kk].z), w0, acc[kk][5]);
      acc[kk][6] = fmaf(bflo(v0[kk].w), w0, acc[kk][6]);
      acc[kk][7] = fmaf(bfhi(v0[kk].w), w0, acc[kk][7]);
      acc[kk][0] = fmaf(bflo(v1[kk].x), w1, acc[kk][0]);
      acc[kk][1] = fmaf(bfhi(v1[kk].x), w1, acc[kk][1]);
      acc[kk][2] = fmaf(bflo(v1[kk].y), w1, acc[kk][2]);
      acc[kk][3] = fmaf(bfhi(v1[kk].y), w1, acc[kk][3]);
      acc[kk][4] = fmaf(bflo(v1[kk].z), w1, acc[kk][4]);
      acc[kk][5] = fmaf(bfhi(v1[kk].z), w1, acc[kk][5]);
      acc[kk][6] = fmaf(bflo(v1[kk].w), w1, acc[kk][6]);
      acc[kk][7] = fmaf(bfhi(v1[kk].w), w1, acc[kk][7]);
    }
  }
  if (e < e1) {
    uint2 p0 = ecw[e];
    float w0 = __uint_as_float(p0.y);
#pragma unroll
    for (int kk = 0; kk < CH; ++kk) {
      uint4 v0 = hp[(size_t)p0.x * RC + kk * 4 + quad];
      acc[kk][0] = fmaf(bflo(v0.x), w0, acc[kk][0]);
      acc[kk][1] = fmaf(bfhi(v0.x), w0, acc[kk][1]);
      acc[kk][2] = fmaf(bflo(v0.y), w0, acc[kk][2]);
      acc[kk][3] = fmaf(bfhi(v0.y), w0, acc[kk][3]);
      acc[kk][4] = fmaf(bflo(v0.z), w0, acc[kk][4]);
      acc[kk][5] = fmaf(bfhi(v0.z), w0, acc[kk][5]);
      acc[kk][6] = fmaf(bflo(v0.w), w0, acc[kk][6]);
      acc[kk][7] = fmaf(bfhi(v0.w), w0, acc[kk][7]);
    }
  }

  // pack fp32 accumulators -> bf16 A-fragments
  v8s af[CH];
#pragma unroll
  for (int kk = 0; kk < CH; ++kk)
#pragma unroll
    for (int j = 0; j < 8; ++j)
      af[kk][j] = (short)f2bf(acc[kk][j]);

  // GEMM: 8 column tiles of 16
#pragma unroll
  for (int t = 0; t < 8; ++t) {
    v4f d = {0.f, 0.f, 0.f, 0.f};
#pragma unroll
    for (int kk = 0; kk < CH; ++kk) {
      v8s bf = *(const v8s*)(WT + (size_t)(t * 16 + l15) * K + kk * 32 + quad * 8);
      d = __builtin_amdgcn_mfma_f32_16x16x32_bf16(af[kk], bf, d, 0, 0, 0);
    }
    float bias = b[t * 16 + l15];
#pragma unroll
    for (int i = 0; i < 4; ++i) {
      int r = nodeBase + quad * 4 + i;
      if (r < N) {
        float o = fmaxf(d[i] + bias, 0.f);
        C[(size_t)r * 128 + t * 16 + l15] = f2bf(o);
      }
    }
  }
}

// ---------------- mean pool over sorted batch_idx ----------------
__global__ void k_pool(const unsigned short* __restrict__ h, const int* __restrict__ batch,
                       float* __restrict__ out, int N, int G) {
  int g = blockIdx.x;
  int tid = threadIdx.x;
  int lo = 0, hi = N;
  while (lo < hi) { int mid = (lo + hi) >> 1; if (batch[mid] < g) lo = mid + 1; else hi = mid; }
  int s = lo;
  hi = N;
  while (lo < hi) { int mid = (lo + hi) >> 1; if (batch[mid] < g + 1) lo = mid + 1; else hi = mid; }
  int e = lo;
  float acc = 0.f;
  for (int n = s; n < e; ++n) acc += bf2f(h[(size_t)n * 128 + tid]);
  float cnt = (float)(e - s);
  out[(size_t)g * 128 + tid] = acc / fmaxf(cnt, 1.f);
}

extern "C" void kernel_launch(void* const* d_in, const int* in_sizes, int n_in,
                              void* d_out, int out_size, void* d_ws, size_t ws_size,
                              hipStream_t stream) {
  const float* x  = (const float*)d_in[0];
  const int* ei   = (const int*)d_in[1];
  const int* batch = (const int*)d_in[2];
  const float* W1 = (const float*)d_in[3];
  const float* b1 = (const float*)d_in[4];
  const float* W2 = (const float*)d_in[5];
  const float* b2 = (const float*)d_in[6];
  const float* W3 = (const float*)d_in[7];
  const float* b3 = (const float*)d_in[8];
  float* out = (float*)d_out;
  int N = in_sizes[2];
  int E = in_sizes[1] / 2;
  int G = out_size / HD;
  const int* src = ei;
  const int* dst = ei + E;

  size_t off = 0;
  char* ws = (char*)d_ws;
  auto alloc = [&](size_t bytes) -> void* {
    void* p = ws + off;
    off += (bytes + 255) & ~(size_t)255;
    return p;
  };
  int*   deg    = (int*)alloc((size_t)N * 4);
  float* dinv   = (float*)alloc((size_t)N * 4);
  int*   rowptr = (int*)alloc((size_t)(N + 1) * 4);
  int*   cursor = (int*)alloc((size_t)N * 4);
  uint2* ecw    = (uint2*)alloc((size_t)E * 8);
  int*   bsum   = (int*)alloc(256 * 4);
  int*   boff   = (int*)alloc(256 * 4);
  unsigned short* xb  = (unsigned short*)alloc((size_t)N * 32 * 2);
  unsigned short* hA  = (unsigned short*)alloc((size_t)N * HD * 2);
  unsigned short* hB  = (unsigned short*)alloc((size_t)N * HD * 2);
  unsigned short* W1T = (unsigned short*)alloc(128 * 32 * 2);
  unsigned short* W2T = (unsigned short*)alloc(128 * 128 * 2);
  unsigned short* W3T = (unsigned short*)alloc(128 * 128 * 2);
  (void)ws_size; (void)n_in;

  int nb1024 = (N + 1023) / 1024;
  k_zero_i32<<<(N + 255) / 256, 256, 0, stream>>>(deg, N);
  k_degree<<<(E + 255) / 256, 256, 0, stream>>>(dst, deg, E);
  k_dinv<<<(N + 255) / 256, 256, 0, stream>>>(deg, dinv, N);
  k_scan1<<<nb1024, 256, 0, stream>>>(deg, bsum, N);
  k_scan2<<<1, 256, 0, stream>>>(bsum, boff, nb1024);
  k_scan3<<<nb1024, 256, 0, stream>>>(deg, boff, rowptr, cursor, N);
  k_scatter<<<(E + 255) / 256, 256, 0, stream>>>(src, dst, dinv, cursor, ecw, E);
  k_wt<<<128, 128, 0, stream>>>(W1, W1T, DIN, 32);
  k_wt<<<128, 128, 0, stream>>>(W2, W2T, 128, 128);
  k_wt<<<128, 128, 0, stream>>>(W3, W3T, 128, 128);
  k_xcast<<<(N * 32 + 255) / 256, 256, 0, stream>>>(x, xb, N);

  int fusedBlocks = (N + 63) / 64;   // 4 waves x 16 nodes per block
  k_fused<32><<<fusedBlocks, 256, 0, stream>>>(xb, W1T, b1, rowptr, ecw, dinv, hA, N);
  k_fused<128><<<fusedBlocks, 256, 0, stream>>>(hA, W2T, b2, rowptr, ecw, dinv, hB, N);
  k_fused<128><<<fusedBlocks, 256, 0, stream>>>(hB, W3T, b3, rowptr, ecw, dinv, hA, N);
  k_pool<<<G, 128, 0, stream>>>(hA, batch, out, N, G);
}